// Round 1
// baseline (430.884 us; speedup 1.0000x reference)
//
#include <hip/hip_runtime.h>
#include <math.h>

#define BS_TOK 16384   // B*S
#define DIM    2048    // D
#define NEXP   64      // E
#define DHID   1024    // D/2
#define GKS    4       // gate k-split
#define KSL    (DIM / GKS)

typedef __attribute__((ext_vector_type(8))) _Float16 f16x8;
typedef __attribute__((ext_vector_type(4))) float    f32x4;

#define GLOBAL_AS const __attribute__((address_space(1))) void*
#define LDS_AS    __attribute__((address_space(3))) void*

__device__ __forceinline__ float gelu_f(float x) {
  return 0.5f * x * (1.0f + erff(x * 0.70710678118654752440f));
}

// ---------------- LayerNorm -> f16 H : one wave per token, no LDS ----------------
__global__ __launch_bounds__(256) void ln_kernel(const float* __restrict__ X,
                                                 const float* __restrict__ gamma,
                                                 const float* __restrict__ beta,
                                                 _Float16* __restrict__ H) {
  const int tid  = threadIdx.x;
  const int w    = tid >> 6, lane = tid & 63;
  const int t    = blockIdx.x * 4 + w;
  const float* xr = X + (size_t)t * DIM;
  float4 xv[8];
#pragma unroll
  for (int j = 0; j < 4; ++j) {
    const int c0 = (j * 64 + lane) * 8;
    xv[j * 2]     = *(const float4*)(xr + c0);
    xv[j * 2 + 1] = *(const float4*)(xr + c0 + 4);
  }
  float s = 0.f, q = 0.f;
#pragma unroll
  for (int j = 0; j < 8; ++j) {
    s += (xv[j].x + xv[j].y) + (xv[j].z + xv[j].w);
    q += (xv[j].x * xv[j].x + xv[j].y * xv[j].y) + (xv[j].z * xv[j].z + xv[j].w * xv[j].w);
  }
#pragma unroll
  for (int off = 32; off > 0; off >>= 1) {
    s += __shfl_xor(s, off);
    q += __shfl_xor(q, off);
  }
  const float mu  = s * (1.0f / DIM);
  const float var = q * (1.0f / DIM) - mu * mu;
  const float rs  = rsqrtf(var + 1e-5f);
#pragma unroll
  for (int j = 0; j < 4; ++j) {
    const int c0 = (j * 64 + lane) * 8;
    const float4 g0 = *(const float4*)(gamma + c0);
    const float4 g1 = *(const float4*)(gamma + c0 + 4);
    const float4 b0 = *(const float4*)(beta + c0);
    const float4 b1 = *(const float4*)(beta + c0 + 4);
    const float4 a = xv[j * 2], b = xv[j * 2 + 1];
    f16x8 h;
    h[0] = (_Float16)((a.x - mu) * rs * g0.x + b0.x);
    h[1] = (_Float16)((a.y - mu) * rs * g0.y + b0.y);
    h[2] = (_Float16)((a.z - mu) * rs * g0.z + b0.z);
    h[3] = (_Float16)((a.w - mu) * rs * g0.w + b0.w);
    h[4] = (_Float16)((b.x - mu) * rs * g1.x + b1.x);
    h[5] = (_Float16)((b.y - mu) * rs * g1.y + b1.y);
    h[6] = (_Float16)((b.z - mu) * rs * g1.z + b1.z);
    h[7] = (_Float16)((b.w - mu) * rs * g1.w + b1.w);
    *(f16x8*)(H + (size_t)t * DIM + c0) = h;
  }
}

// ---------------- W1 fp32 -> f16 ----------------
__global__ __launch_bounds__(256) void w1cast_kernel(const float* __restrict__ W1,
                                                     _Float16* __restrict__ W1h) {
  const int i = (blockIdx.x * 256 + threadIdx.x) * 8;
  const float4 a = *(const float4*)(W1 + i);
  const float4 b = *(const float4*)(W1 + i + 4);
  f16x8 o;
  o[0] = (_Float16)a.x; o[1] = (_Float16)a.y; o[2] = (_Float16)a.z; o[3] = (_Float16)a.w;
  o[4] = (_Float16)b.x; o[5] = (_Float16)b.y; o[6] = (_Float16)b.z; o[7] = (_Float16)b.w;
  *(f16x8*)(W1h + i) = o;
}

// -------- gate partials: logitsP[ks] = X[:, ks] . Wg[:, ks]^T ----------
// 128x64 tile, 8x8 micro (64 acc VGPRs), 128 threads, k-split 4.
// 8x8 micro doubles FMA-per-LDS-read (16 vs 8) -> halves the LDS-BW wall.
// Strides 132/68: staging stores and float4 reads are <=2-way (free).
#define GT_M 128
#define PX   132
#define PW   68
__global__ __launch_bounds__(128) void gate_kernel(const float* __restrict__ X,
                                                   const float* __restrict__ Wg,
                                                   float* __restrict__ logitsP) {
  __shared__ float sX[16][PX];   // [k][m]
  __shared__ float sW[16][PW];   // [k][e]
  const int tid  = threadIdx.x;
  const int m0   = blockIdx.x * GT_M;
  const int k0   = blockIdx.y * KSL;
  const int srow = tid >> 2;      // 0..31 staging row base
  const int skq  = tid & 3;       // k-quad
  const int ty   = tid >> 3;      // 0..15 token group (8 tokens)
  const int tx   = tid & 7;       // 0..7  expert group (8 experts)
  const float* xb = X  + (size_t)(m0 + srow) * DIM + k0 + skq * 4;
  const float* wb = Wg + (size_t)srow * DIM + k0 + skq * 4;
  float acc[8][8] = {};
  float4 rx[4], rw[2];
#pragma unroll
  for (int r = 0; r < 4; ++r) rx[r] = *(const float4*)(xb + (size_t)(r * 32) * DIM);
#pragma unroll
  for (int r = 0; r < 2; ++r) rw[r] = *(const float4*)(wb + (size_t)(r * 32) * DIM);
  for (int kt = 0; kt < KSL; kt += 16) {
    __syncthreads();
#pragma unroll
    for (int r = 0; r < 4; ++r) {
      sX[skq * 4 + 0][srow + r * 32] = rx[r].x;
      sX[skq * 4 + 1][srow + r * 32] = rx[r].y;
      sX[skq * 4 + 2][srow + r * 32] = rx[r].z;
      sX[skq * 4 + 3][srow + r * 32] = rx[r].w;
    }
#pragma unroll
    for (int r = 0; r < 2; ++r) {
      sW[skq * 4 + 0][srow + r * 32] = rw[r].x;
      sW[skq * 4 + 1][srow + r * 32] = rw[r].y;
      sW[skq * 4 + 2][srow + r * 32] = rw[r].z;
      sW[skq * 4 + 3][srow + r * 32] = rw[r].w;
    }
    const int ktn = (kt + 16 < KSL) ? kt + 16 : 0;   // harmless reload on last iter
#pragma unroll
    for (int r = 0; r < 4; ++r) rx[r] = *(const float4*)(xb + (size_t)(r * 32) * DIM + ktn);
#pragma unroll
    for (int r = 0; r < 2; ++r) rw[r] = *(const float4*)(wb + (size_t)(r * 32) * DIM + ktn);
    __syncthreads();
#pragma unroll
    for (int k = 0; k < 16; ++k) {
      const float4 a0 = *(const float4*)&sX[k][ty * 8];
      const float4 a1 = *(const float4*)&sX[k][ty * 8 + 4];
      const float4 b0 = *(const float4*)&sW[k][tx * 8];
      const float4 b1 = *(const float4*)&sW[k][tx * 8 + 4];
      const float av[8] = {a0.x, a0.y, a0.z, a0.w, a1.x, a1.y, a1.z, a1.w};
      const float bv[8] = {b0.x, b0.y, b0.z, b0.w, b1.x, b1.y, b1.z, b1.w};
#pragma unroll
      for (int i = 0; i < 8; ++i)
#pragma unroll
        for (int j = 0; j < 8; ++j) acc[i][j] += av[i] * bv[j];
    }
  }
  float* op = logitsP + (size_t)blockIdx.y * ((size_t)BS_TOK * NEXP)
            + (size_t)(m0 + ty * 8) * NEXP + tx * 8;
#pragma unroll
  for (int i = 0; i < 8; ++i) {
    float4 o0, o1;
    o0.x = acc[i][0]; o0.y = acc[i][1]; o0.z = acc[i][2]; o0.w = acc[i][3];
    o1.x = acc[i][4]; o1.y = acc[i][5]; o1.z = acc[i][6]; o1.w = acc[i][7];
    *(float4*)(op + (size_t)i * NEXP)     = o0;
    *(float4*)(op + (size_t)i * NEXP + 4) = o1;
  }
}

// ------- predictor GEMM: H1 = gelu(H . W1^T); z[t] += sum_n H1*W2 (fused) -------
// XCD-swizzled 1-D grid. Double-buffered LDS: STAGE(next) issued BEFORE the
// ds_read+MFMA of the current tile, so the global_load_lds latency hides under
// 16 MFMAs instead of being drained immediately at a barrier (T3 minimum 2-phase).
__global__ __launch_bounds__(256) void g2_kernel(const _Float16* __restrict__ H,
                                                 const _Float16* __restrict__ W1h,
                                                 const float* __restrict__ W2,
                                                 float* __restrict__ diffz) {
  __shared__ __align__(16) _Float16 sA[2][128 * 32];
  __shared__ __align__(16) _Float16 sB[2][128 * 32];
  const int bid = blockIdx.x;
  const int c   = bid & 7;
  const int j   = bid >> 3;
  const int m0  = (c * 16 + (j >> 3)) * 128;
  const int n0  = (j & 7) * 128;
  const int tid  = threadIdx.x;
  const int w    = tid >> 6, lane = tid & 63;
  const int wr   = w >> 1,  wc   = w & 1;
  const int col  = lane & 15, quad = lane >> 4;
  const int row0 = tid >> 2,  kp = tid & 3;
  const int row1 = row0 + 64;
  const _Float16* gA0 = H   + (size_t)(m0 + row0) * DIM + kp * 8;
  const _Float16* gA1 = H   + (size_t)(m0 + row1) * DIM + kp * 8;
  const _Float16* gB0 = W1h + (size_t)(n0 + row0) * DIM + kp * 8;
  const _Float16* gB1 = W1h + (size_t)(n0 + row1) * DIM + kp * 8;
  f32x4 acc[4][4] = {};
#define G2_STAGE(buf, off)                                                                              \
  do {                                                                                                  \
    __builtin_amdgcn_global_load_lds((GLOBAL_AS)(gA0 + (off)), (LDS_AS)(sA[buf] + tid * 8), 16, 0, 0);  \
    __builtin_amdgcn_global_load_lds((GLOBAL_AS)(gA1 + (off)), (LDS_AS)(sA[buf] + (256 + tid) * 8), 16, 0, 0); \
    __builtin_amdgcn_global_load_lds((GLOBAL_AS)(gB0 + (off)), (LDS_AS)(sB[buf] + tid * 8), 16, 0, 0);  \
    __builtin_amdgcn_global_load_lds((GLOBAL_AS)(gB1 + (off)), (LDS_AS)(sB[buf] + (256 + tid) * 8), 16, 0, 0); \
  } while (0)
  G2_STAGE(0, 0);
  __syncthreads();
  int cur = 0;
  for (int kt = 0; kt < DIM; kt += 32) {
    if (kt + 32 < DIM) G2_STAGE(cur ^ 1, kt + 32);   // prefetch next tile (in flight across compute)
    f16x8 af[4], bf[4];
#pragma unroll
    for (int mi = 0; mi < 4; ++mi)
      af[mi] = *(const f16x8*)(sA[cur] + (wr * 64 + mi * 16 + col) * 32 + quad * 8);
#pragma unroll
    for (int ni = 0; ni < 4; ++ni)
      bf[ni] = *(const f16x8*)(sB[cur] + (wc * 64 + ni * 16 + col) * 32 + quad * 8);
#pragma unroll
    for (int mi = 0; mi < 4; ++mi)
#pragma unroll
      for (int ni = 0; ni < 4; ++ni)
        acc[mi][ni] = __builtin_amdgcn_mfma_f32_16x16x32_f16(af[mi], bf[ni], acc[mi][ni], 0, 0, 0);
    __syncthreads();   // drains vmcnt: next buffer fully staged; all waves done reading cur
    cur ^= 1;
  }
  // epilogue: gelu -> * W2 -> reduce over the 128 n-cols this block owns
  float w2v[4];
#pragma unroll
  for (int ni = 0; ni < 4; ++ni) w2v[ni] = W2[n0 + wc * 64 + ni * 16 + col];
#pragma unroll
  for (int mi = 0; mi < 4; ++mi) {
#pragma unroll
    for (int reg = 0; reg < 4; ++reg) {
      float v = 0.f;
#pragma unroll
      for (int ni = 0; ni < 4; ++ni) v += gelu_f(acc[mi][ni][reg]) * w2v[ni];
      v += __shfl_xor(v, 1);
      v += __shfl_xor(v, 2);
      v += __shfl_xor(v, 4);
      v += __shfl_xor(v, 8);
      if (col == 0)
        atomicAdd(diffz + m0 + wr * 64 + mi * 16 + quad * 4 + reg, v);
    }
  }
}

// ---------------- per-token finalize: one wave per token, 32 tokens/block ----------------
__global__ __launch_bounds__(256) void finalize_kernel(const float* __restrict__ logitsP,
                                                       const float* __restrict__ diffz,
                                                       float* __restrict__ out_idx,
                                                       float* __restrict__ out_scores,
                                                       float* __restrict__ out_probs,
                                                       float* __restrict__ imp_acc,
                                                       float* __restrict__ load_acc) {
  const int tid  = threadIdx.x;
  const int w    = tid >> 6, lane = tid & 63;
  const size_t PS = (size_t)BS_TOK * NEXP;
  float acc_imp = 0.f, acc_load = 0.f;
  for (int it = 0; it < 8; ++it) {
    const int t    = blockIdx.x * 32 + it * 4 + w;
    const float* lp = logitsP + (size_t)t * NEXP + lane;
    const float L  = ((lp[0] + lp[PS]) + lp[2 * PS]) + lp[3 * PS];
    const float z  = diffz[t];
    const float d  = 1.0f / (1.0f + expf(-z));
    const float l  = L / (1.0f + d);          // TEMP == 1
    // softmax
    float m = l;
#pragma unroll
    for (int off = 32; off > 0; off >>= 1) m = fmaxf(m, __shfl_xor(m, off));
    float p = expf(l - m);
    float s = p;
#pragma unroll
    for (int off = 32; off > 0; off >>= 1) s += __shfl_xor(s, off);
    p /= s;
    // top-1 (jax tie-break: lower index wins)
    float v = l; int bi = lane;
#pragma unroll
    for (int off = 32; off > 0; off >>= 1) {
      const float ov = __shfl_xor(v, off);
      const int   oi = __shfl_xor(bi, off);
      if (ov > v || (ov == v && oi < bi)) { v = ov; bi = oi; }
    }
    const int i1 = bi;
    // top-2
    float v2 = (lane == i1) ? -INFINITY : l;
    int bi2 = lane;
#pragma unroll
    for (int off = 32; off > 0; off >>= 1) {
      const float ov = __shfl_xor(v2, off);
      const int   oi = __shfl_xor(bi2, off);
      if (ov > v2 || (ov == v2 && oi < bi2)) { v2 = ov; bi2 = oi; }
    }
    const int i2 = bi2;
    const float p1 = __shfl(p, i1);
    const float p2 = __shfl(p, i2);
    const float s1 = (1.0f - p1) + p1;        // straight-through, fp32-faithful
    const float s2 = (1.0f - p2) + p2;
    const float den = fmaxf(s1 + s2, 1e-9f);
    if (lane == 0) {
      out_idx[t * 2]        = (float)i1;
      out_idx[t * 2 + 1]    = (float)i2;
      out_scores[t * 2]     = s1 / den;
      out_scores[t * 2 + 1] = s2 / den;
    }
    out_probs[(size_t)t * NEXP + lane] = p;
    acc_imp  += p;
    acc_load += (lane == i1 || lane == i2) ? 1.0f : 0.0f;
  }
  __shared__ float s_imp[256];
  __shared__ float s_hard[256];
  s_imp[tid]  = acc_imp;
  s_hard[tid] = acc_load;
  __syncthreads();
  if (tid < 64) {
    const float si = s_imp[tid] + s_imp[64 + tid] + s_imp[128 + tid] + s_imp[192 + tid];
    const float sl = s_hard[tid] + s_hard[64 + tid] + s_hard[128 + tid] + s_hard[192 + tid];
    atomicAdd(imp_acc + tid, si);
    atomicAdd(load_acc + tid, sl);
  }
}

// ---------------- importance/load scale ----------------
__global__ void scale_kernel(const float* __restrict__ acc,
                             float* __restrict__ out_imp,
                             float* __restrict__ out_load) {
  const int tid = threadIdx.x;
  const float inv = 1.0f / 16384.0f;
  if (tid < 64)       out_imp[tid]        = acc[tid] * inv;
  else if (tid < 128) out_load[tid - 64]  = acc[tid] * inv;
}

extern "C" void kernel_launch(void* const* d_in, const int* in_sizes, int n_in,
                              void* d_out, int out_size, void* d_ws, size_t ws_size,
                              hipStream_t stream) {
  (void)in_sizes; (void)n_in; (void)out_size; (void)ws_size;
  const float* X     = (const float*)d_in[0];
  const float* Wg    = (const float*)d_in[1];
  const float* gamma = (const float*)d_in[2];
  const float* beta  = (const float*)d_in[3];
  const float* W1    = (const float*)d_in[4];
  const float* W2    = (const float*)d_in[5];
  float* out = (float*)d_out;

  char* ws = (char*)d_ws;
  _Float16* H       = (_Float16*)(ws);                    // 64 MB
  _Float16* W1h     = (_Float16*)(ws + 67108864ull);      // 4 MB
  float*    logitsP = (float*)  (ws + 71303168ull);       // 16 MB (4 k-split partials)
  float*    diffz   = (float*)  (ws + 88080384ull);       // 64 KB
  float*    accs    = (float*)  (ws + 88145920ull);       // 512 B (imp[64], load[64])

  // out layout (all float32): idx[32768] | scores[32768] | probs[1048576] | imp[64] | load[64]
  float* out_idx    = out;
  float* out_scores = out + 32768;
  float* out_probs  = out + 65536;
  float* out_imp    = out + 1114112;
  float* out_load   = out + 1114176;

  hipMemsetAsync(diffz, 0, 65536ull + 512ull, stream);
  ln_kernel<<<BS_TOK / 4, 256, 0, stream>>>(X, gamma, beta, H);
  w1cast_kernel<<<(DHID * DIM) / (256 * 8), 256, 0, stream>>>(W1, W1h);
  gate_kernel<<<dim3(BS_TOK / GT_M, GKS), 128, 0, stream>>>(X, Wg, logitsP);
  g2_kernel<<<(DHID / 128) * (BS_TOK / 128), 256, 0, stream>>>(H, W1h, W2, diffz);
  finalize_kernel<<<BS_TOK / 32, 256, 0, stream>>>(logitsP, diffz, out_idx, out_scores,
                                                   out_probs, accs, accs + 64);
  scale_kernel<<<1, 128, 0, stream>>>(accs, out_imp, out_load);
}

// Round 2
// 415.244 us; speedup vs baseline: 1.0377x; 1.0377x over previous
//
#include <hip/hip_runtime.h>
#include <math.h>

#define BS_TOK 16384   // B*S
#define DIM    2048    // D
#define NEXP   64      // E
#define DHID   1024    // D/2
#define GKS    4       // gate k-split
#define KSL    (DIM / GKS)

typedef __attribute__((ext_vector_type(8))) _Float16 f16x8;
typedef __attribute__((ext_vector_type(4))) float    f32x4;

#define GLOBAL_AS const __attribute__((address_space(1))) void*
#define LDS_AS    __attribute__((address_space(3))) void*

__device__ __forceinline__ float gelu_f(float x) {
  return 0.5f * x * (1.0f + erff(x * 0.70710678118654752440f));
}

// ---------------- LayerNorm -> f16 H : one wave per token, no LDS ----------------
__global__ __launch_bounds__(256) void ln_kernel(const float* __restrict__ X,
                                                 const float* __restrict__ gamma,
                                                 const float* __restrict__ beta,
                                                 _Float16* __restrict__ H) {
  const int tid  = threadIdx.x;
  const int w    = tid >> 6, lane = tid & 63;
  const int t    = blockIdx.x * 4 + w;
  const float* xr = X + (size_t)t * DIM;
  float4 xv[8];
#pragma unroll
  for (int j = 0; j < 4; ++j) {
    const int c0 = (j * 64 + lane) * 8;
    xv[j * 2]     = *(const float4*)(xr + c0);
    xv[j * 2 + 1] = *(const float4*)(xr + c0 + 4);
  }
  float s = 0.f, q = 0.f;
#pragma unroll
  for (int j = 0; j < 8; ++j) {
    s += (xv[j].x + xv[j].y) + (xv[j].z + xv[j].w);
    q += (xv[j].x * xv[j].x + xv[j].y * xv[j].y) + (xv[j].z * xv[j].z + xv[j].w * xv[j].w);
  }
#pragma unroll
  for (int off = 32; off > 0; off >>= 1) {
    s += __shfl_xor(s, off);
    q += __shfl_xor(q, off);
  }
  const float mu  = s * (1.0f / DIM);
  const float var = q * (1.0f / DIM) - mu * mu;
  const float rs  = rsqrtf(var + 1e-5f);
#pragma unroll
  for (int j = 0; j < 4; ++j) {
    const int c0 = (j * 64 + lane) * 8;
    const float4 g0 = *(const float4*)(gamma + c0);
    const float4 g1 = *(const float4*)(gamma + c0 + 4);
    const float4 b0 = *(const float4*)(beta + c0);
    const float4 b1 = *(const float4*)(beta + c0 + 4);
    const float4 a = xv[j * 2], b = xv[j * 2 + 1];
    f16x8 h;
    h[0] = (_Float16)((a.x - mu) * rs * g0.x + b0.x);
    h[1] = (_Float16)((a.y - mu) * rs * g0.y + b0.y);
    h[2] = (_Float16)((a.z - mu) * rs * g0.z + b0.z);
    h[3] = (_Float16)((a.w - mu) * rs * g0.w + b0.w);
    h[4] = (_Float16)((b.x - mu) * rs * g1.x + b1.x);
    h[5] = (_Float16)((b.y - mu) * rs * g1.y + b1.y);
    h[6] = (_Float16)((b.z - mu) * rs * g1.z + b1.z);
    h[7] = (_Float16)((b.w - mu) * rs * g1.w + b1.w);
    *(f16x8*)(H + (size_t)t * DIM + c0) = h;
  }
}

// ---------------- W1 fp32 -> f16 ----------------
__global__ __launch_bounds__(256) void w1cast_kernel(const float* __restrict__ W1,
                                                     _Float16* __restrict__ W1h) {
  const int i = (blockIdx.x * 256 + threadIdx.x) * 8;
  const float4 a = *(const float4*)(W1 + i);
  const float4 b = *(const float4*)(W1 + i + 4);
  f16x8 o;
  o[0] = (_Float16)a.x; o[1] = (_Float16)a.y; o[2] = (_Float16)a.z; o[3] = (_Float16)a.w;
  o[4] = (_Float16)b.x; o[5] = (_Float16)b.y; o[6] = (_Float16)b.z; o[7] = (_Float16)b.w;
  *(f16x8*)(W1h + i) = o;
}

// -------- gate partials: logitsP[ks] = X[:, ks] . Wg[:, ks]^T ----------
// (round-0 version: 64x64 tile, 4x4 micro, 256 threads, 1024-block grid)
__global__ __launch_bounds__(256) void gate_kernel(const float* __restrict__ X,
                                                   const float* __restrict__ Wg,
                                                   float* __restrict__ logitsP) {
  __shared__ float sX[16][68];   // [k][m], padded
  __shared__ float sW[16][68];   // [k][e], padded
  const int tid  = threadIdx.x;
  const int m0   = blockIdx.x * 64;
  const int k0   = blockIdx.y * KSL;
  const int srow = tid >> 2;      // 0..63 staging row
  const int skq  = tid & 3;       // k-quad
  const int ty   = tid >> 4;      // 0..15 token group (4 tokens)
  const int tx   = tid & 15;      // 0..15 expert group (4 experts)
  const float* xb = X  + (size_t)(m0 + srow) * DIM + k0 + skq * 4;
  const float* wb = Wg + (size_t)srow * DIM + k0 + skq * 4;
  float acc[4][4] = {};
  float4 rx = *(const float4*)xb;
  float4 rw = *(const float4*)wb;
  for (int kt = 0; kt < KSL; kt += 16) {
    __syncthreads();
    sX[skq * 4 + 0][srow] = rx.x;
    sX[skq * 4 + 1][srow] = rx.y;
    sX[skq * 4 + 2][srow] = rx.z;
    sX[skq * 4 + 3][srow] = rx.w;
    sW[skq * 4 + 0][srow] = rw.x;
    sW[skq * 4 + 1][srow] = rw.y;
    sW[skq * 4 + 2][srow] = rw.z;
    sW[skq * 4 + 3][srow] = rw.w;
    const int ktn = (kt + 16 < KSL) ? kt + 16 : 0;   // harmless reload on last iter
    rx = *(const float4*)(xb + ktn);
    rw = *(const float4*)(wb + ktn);
    __syncthreads();
#pragma unroll
    for (int k = 0; k < 16; ++k) {
      const float4 a4 = *(const float4*)&sX[k][ty * 4];
      const float4 b4 = *(const float4*)&sW[k][tx * 4];
      const float av[4] = {a4.x, a4.y, a4.z, a4.w};
      const float bv[4] = {b4.x, b4.y, b4.z, b4.w};
#pragma unroll
      for (int i = 0; i < 4; ++i)
#pragma unroll
        for (int j = 0; j < 4; ++j) acc[i][j] += av[i] * bv[j];
    }
  }
  float* op = logitsP + (size_t)blockIdx.y * (BS_TOK * NEXP)
            + (size_t)(m0 + ty * 4) * NEXP + tx * 4;
#pragma unroll
  for (int i = 0; i < 4; ++i) {
    float4 o;
    o.x = acc[i][0]; o.y = acc[i][1]; o.z = acc[i][2]; o.w = acc[i][3];
    *(float4*)(op + (size_t)i * NEXP) = o;
  }
}

// ------- predictor GEMM: H1 = gelu(H . W1^T); z[t] += sum_n H1*W2 (fused) -------
// 256x256 tile, 8 waves (2Mx4N), BK=32, 3 LDS buffers, depth-2 prefetch with
// COUNTED vmcnt (never 0 in steady state) + raw s_barrier (T3/T4), XOR-swizzled
// LDS k-slots (T2: pre-swizzled global source, linear LDS dest, swizzled read),
// setprio around MFMA cluster (T5). Grid = 256 blocks = 1 block/CU exactly.
#define G2BM 256
#define G2BN 256
#define G2BK 32
#define G2NS (DIM / G2BK)   // 64 k-steps

__global__ __launch_bounds__(512, 2) void g2_kernel(const _Float16* __restrict__ H,
                                                    const _Float16* __restrict__ W1h,
                                                    const float* __restrict__ W2,
                                                    float* __restrict__ diffz) {
  __shared__ __align__(16) _Float16 sA[3][G2BM * G2BK];
  __shared__ __align__(16) _Float16 sB[3][G2BN * G2BK];
  const int bid = blockIdx.x;
  const int m0  = (bid >> 2) * G2BM;
  const int n0  = (bid & 3) * G2BN;
  const int tid  = threadIdx.x;
  const int lane = tid & 63;
  const int w    = tid >> 6;
  const int wr   = w >> 2, wc = w & 3;        // 2 x 4 wave grid
  const int col  = lane & 15, quad = lane >> 4;
  // staging geometry: thread t covers rows (t>>2) and 128+(t>>2), 16B k-slot each.
  // global k-slot is pre-swizzled so linear LDS dest holds swizzled layout:
  //   LDS (row, slot) holds global k-quad  slot ^ ((row>>1)&3)
  const int srow = tid >> 2;                           // 0..127
  const int ks   = (tid & 3) ^ ((tid >> 3) & 3);       // swizzled source k-slot
  const _Float16* gA0 = H   + (size_t)(m0 + srow)       * DIM + ks * 8;
  const _Float16* gA1 = H   + (size_t)(m0 + 128 + srow) * DIM + ks * 8;
  const _Float16* gB0 = W1h + (size_t)(n0 + srow)       * DIM + ks * 8;
  const _Float16* gB1 = W1h + (size_t)(n0 + 128 + srow) * DIM + ks * 8;
  // read-side swizzled k-offset (elements): rows read are base+col, so
  // (row>>1)&3 == (col>>1)&3 for all frags (bases are multiples of 16).
  const int sq = (quad ^ ((col >> 1) & 3)) * 8;
  f32x4 acc[8][4] = {};
#define G2_STAGE(bf_, kt_)                                                                                   \
  do {                                                                                                       \
    __builtin_amdgcn_global_load_lds((GLOBAL_AS)(gA0 + (kt_)), (LDS_AS)(sA[bf_] + tid * 8), 16, 0, 0);       \
    __builtin_amdgcn_global_load_lds((GLOBAL_AS)(gA1 + (kt_)), (LDS_AS)(sA[bf_] + 128 * G2BK + tid * 8), 16, 0, 0); \
    __builtin_amdgcn_global_load_lds((GLOBAL_AS)(gB0 + (kt_)), (LDS_AS)(sB[bf_] + tid * 8), 16, 0, 0);       \
    __builtin_amdgcn_global_load_lds((GLOBAL_AS)(gB1 + (kt_)), (LDS_AS)(sB[bf_] + 128 * G2BK + tid * 8), 16, 0, 0); \
  } while (0)
  // prologue: tiles 0 and 1 in flight (8 loads/thread outstanding)
  G2_STAGE(0, 0);
  G2_STAGE(1, G2BK);
  int cur = 0, pf = 2;   // pf == (cur+2)%3
  for (int s = 0; s < G2NS; ++s) {
    // counted wait: tile s landed, tile s+1 (4 loads) stays in flight.
    if (s == G2NS - 1) asm volatile("s_waitcnt vmcnt(0)" ::: "memory");
    else               asm volatile("s_waitcnt vmcnt(4)" ::: "memory");
    __builtin_amdgcn_s_barrier();   // raw barrier: no vmcnt(0) drain
    if (s + 2 < G2NS) G2_STAGE(pf, (s + 2) * G2BK);
    const _Float16* A = sA[cur];
    const _Float16* B = sB[cur];
    f16x8 af[8], bf[4];
#pragma unroll
    for (int mi = 0; mi < 8; ++mi)
      af[mi] = *(const f16x8*)(A + (wr * 128 + mi * 16 + col) * G2BK + sq);
#pragma unroll
    for (int ni = 0; ni < 4; ++ni)
      bf[ni] = *(const f16x8*)(B + (wc * 64 + ni * 16 + col) * G2BK + sq);
    __builtin_amdgcn_s_setprio(1);
#pragma unroll
    for (int mi = 0; mi < 8; ++mi)
#pragma unroll
      for (int ni = 0; ni < 4; ++ni)
        acc[mi][ni] = __builtin_amdgcn_mfma_f32_16x16x32_f16(af[mi], bf[ni], acc[mi][ni], 0, 0, 0);
    __builtin_amdgcn_s_setprio(0);
    // drain this wave's LDS reads before the next barrier: iteration s+1 stages
    // into buf cur (== (s+3)%3), so reads of buf cur must be complete by then.
    asm volatile("s_waitcnt lgkmcnt(0)" ::: "memory");
    cur = (cur == 2) ? 0 : cur + 1;
    pf  = (pf  == 2) ? 0 : pf  + 1;
  }
#undef G2_STAGE
  // epilogue: gelu -> * W2 -> reduce over the 256 n-cols this block owns
  float w2v[4];
#pragma unroll
  for (int ni = 0; ni < 4; ++ni) w2v[ni] = W2[n0 + wc * 64 + ni * 16 + col];
#pragma unroll
  for (int mi = 0; mi < 8; ++mi) {
#pragma unroll
    for (int reg = 0; reg < 4; ++reg) {
      float v = 0.f;
#pragma unroll
      for (int ni = 0; ni < 4; ++ni) v += gelu_f(acc[mi][ni][reg]) * w2v[ni];
      v += __shfl_xor(v, 1);
      v += __shfl_xor(v, 2);
      v += __shfl_xor(v, 4);
      v += __shfl_xor(v, 8);
      if (col == 0)
        atomicAdd(diffz + m0 + wr * 128 + mi * 16 + quad * 4 + reg, v);
    }
  }
}

// ---------------- per-token finalize: one wave per token, 32 tokens/block ----------------
__global__ __launch_bounds__(256) void finalize_kernel(const float* __restrict__ logitsP,
                                                       const float* __restrict__ diffz,
                                                       float* __restrict__ out_idx,
                                                       float* __restrict__ out_scores,
                                                       float* __restrict__ out_probs,
                                                       float* __restrict__ imp_acc,
                                                       float* __restrict__ load_acc) {
  const int tid  = threadIdx.x;
  const int w    = tid >> 6, lane = tid & 63;
  const size_t PS = (size_t)BS_TOK * NEXP;
  float acc_imp = 0.f, acc_load = 0.f;
  for (int it = 0; it < 8; ++it) {
    const int t    = blockIdx.x * 32 + it * 4 + w;
    const float* lp = logitsP + (size_t)t * NEXP + lane;
    const float L  = ((lp[0] + lp[PS]) + lp[2 * PS]) + lp[3 * PS];
    const float z  = diffz[t];
    const float d  = 1.0f / (1.0f + expf(-z));
    const float l  = L / (1.0f + d);          // TEMP == 1
    // softmax
    float m = l;
#pragma unroll
    for (int off = 32; off > 0; off >>= 1) m = fmaxf(m, __shfl_xor(m, off));
    float p = expf(l - m);
    float s = p;
#pragma unroll
    for (int off = 32; off > 0; off >>= 1) s += __shfl_xor(s, off);
    p /= s;
    // top-1 (jax tie-break: lower index wins)
    float v = l; int bi = lane;
#pragma unroll
    for (int off = 32; off > 0; off >>= 1) {
      const float ov = __shfl_xor(v, off);
      const int   oi = __shfl_xor(bi, off);
      if (ov > v || (ov == v && oi < bi)) { v = ov; bi = oi; }
    }
    const int i1 = bi;
    // top-2
    float v2 = (lane == i1) ? -INFINITY : l;
    int bi2 = lane;
#pragma unroll
    for (int off = 32; off > 0; off >>= 1) {
      const float ov = __shfl_xor(v2, off);
      const int   oi = __shfl_xor(bi2, off);
      if (ov > v2 || (ov == v2 && oi < bi2)) { v2 = ov; bi2 = oi; }
    }
    const int i2 = bi2;
    const float p1 = __shfl(p, i1);
    const float p2 = __shfl(p, i2);
    const float s1 = (1.0f - p1) + p1;        // straight-through, fp32-faithful
    const float s2 = (1.0f - p2) + p2;
    const float den = fmaxf(s1 + s2, 1e-9f);
    if (lane == 0) {
      out_idx[t * 2]        = (float)i1;
      out_idx[t * 2 + 1]    = (float)i2;
      out_scores[t * 2]     = s1 / den;
      out_scores[t * 2 + 1] = s2 / den;
    }
    out_probs[(size_t)t * NEXP + lane] = p;
    acc_imp  += p;
    acc_load += (lane == i1 || lane == i2) ? 1.0f : 0.0f;
  }
  __shared__ float s_imp[256];
  __shared__ float s_hard[256];
  s_imp[tid]  = acc_imp;
  s_hard[tid] = acc_load;
  __syncthreads();
  if (tid < 64) {
    const float si = s_imp[tid] + s_imp[64 + tid] + s_imp[128 + tid] + s_imp[192 + tid];
    const float sl = s_hard[tid] + s_hard[64 + tid] + s_hard[128 + tid] + s_hard[192 + tid];
    atomicAdd(imp_acc + tid, si);
    atomicAdd(load_acc + tid, sl);
  }
}

// ---------------- importance/load scale ----------------
__global__ void scale_kernel(const float* __restrict__ acc,
                             float* __restrict__ out_imp,
                             float* __restrict__ out_load) {
  const int tid = threadIdx.x;
  const float inv = 1.0f / 16384.0f;
  if (tid < 64)       out_imp[tid]        = acc[tid] * inv;
  else if (tid < 128) out_load[tid - 64]  = acc[tid] * inv;
}

extern "C" void kernel_launch(void* const* d_in, const int* in_sizes, int n_in,
                              void* d_out, int out_size, void* d_ws, size_t ws_size,
                              hipStream_t stream) {
  (void)in_sizes; (void)n_in; (void)out_size; (void)ws_size;
  const float* X     = (const float*)d_in[0];
  const float* Wg    = (const float*)d_in[1];
  const float* gamma = (const float*)d_in[2];
  const float* beta  = (const float*)d_in[3];
  const float* W1    = (const float*)d_in[4];
  const float* W2    = (const float*)d_in[5];
  float* out = (float*)d_out;

  char* ws = (char*)d_ws;
  _Float16* H       = (_Float16*)(ws);                    // 64 MB
  _Float16* W1h     = (_Float16*)(ws + 67108864ull);      // 4 MB
  float*    logitsP = (float*)  (ws + 71303168ull);       // 16 MB (4 k-split partials)
  float*    diffz   = (float*)  (ws + 88080384ull);       // 64 KB
  float*    accs    = (float*)  (ws + 88145920ull);       // 512 B (imp[64], load[64])

  // out layout (all float32): idx[32768] | scores[32768] | probs[1048576] | imp[64] | load[64]
  float* out_idx    = out;
  float* out_scores = out + 32768;
  float* out_probs  = out + 65536;
  float* out_imp    = out + 1114112;
  float* out_load   = out + 1114176;

  hipMemsetAsync(diffz, 0, 65536ull + 512ull, stream);
  ln_kernel<<<BS_TOK / 4, 256, 0, stream>>>(X, gamma, beta, H);
  w1cast_kernel<<<(DHID * DIM) / (256 * 8), 256, 0, stream>>>(W1, W1h);
  gate_kernel<<<dim3(BS_TOK / 64, GKS), 256, 0, stream>>>(X, Wg, logitsP);
  g2_kernel<<<(DHID / G2BN) * (BS_TOK / G2BM), 512, 0, stream>>>(H, W1h, W2, diffz);
  finalize_kernel<<<BS_TOK / 32, 256, 0, stream>>>(logitsP, diffz, out_idx, out_scores,
                                                   out_probs, accs, accs + 64);
  scale_kernel<<<1, 128, 0, stream>>>(accs, out_imp, out_load);
}

// Round 3
// 366.720 us; speedup vs baseline: 1.1750x; 1.1323x over previous
//
#include <hip/hip_runtime.h>
#include <math.h>

#define BS_TOK 16384   // B*S
#define DIM    2048    // D
#define NEXP   64      // E
#define DHID   1024    // D/2
#define GKS    4       // gate k-split
#define KSL    (DIM / GKS)

typedef __attribute__((ext_vector_type(8))) _Float16 f16x8;
typedef __attribute__((ext_vector_type(4))) float    f32x4;

#define GLOBAL_AS const __attribute__((address_space(1))) void*
#define LDS_AS    __attribute__((address_space(3))) void*

__device__ __forceinline__ float gelu_f(float x) {
  return 0.5f * x * (1.0f + erff(x * 0.70710678118654752440f));
}

// ---------------- LayerNorm -> f16 H : one wave per token, no LDS ----------------
__global__ __launch_bounds__(256) void ln_kernel(const float* __restrict__ X,
                                                 const float* __restrict__ gamma,
                                                 const float* __restrict__ beta,
                                                 _Float16* __restrict__ H) {
  const int tid  = threadIdx.x;
  const int w    = tid >> 6, lane = tid & 63;
  const int t    = blockIdx.x * 4 + w;
  const float* xr = X + (size_t)t * DIM;
  float4 xv[8];
#pragma unroll
  for (int j = 0; j < 4; ++j) {
    const int c0 = (j * 64 + lane) * 8;
    xv[j * 2]     = *(const float4*)(xr + c0);
    xv[j * 2 + 1] = *(const float4*)(xr + c0 + 4);
  }
  float s = 0.f, q = 0.f;
#pragma unroll
  for (int j = 0; j < 8; ++j) {
    s += (xv[j].x + xv[j].y) + (xv[j].z + xv[j].w);
    q += (xv[j].x * xv[j].x + xv[j].y * xv[j].y) + (xv[j].z * xv[j].z + xv[j].w * xv[j].w);
  }
#pragma unroll
  for (int off = 32; off > 0; off >>= 1) {
    s += __shfl_xor(s, off);
    q += __shfl_xor(q, off);
  }
  const float mu  = s * (1.0f / DIM);
  const float var = q * (1.0f / DIM) - mu * mu;
  const float rs  = rsqrtf(var + 1e-5f);
#pragma unroll
  for (int j = 0; j < 4; ++j) {
    const int c0 = (j * 64 + lane) * 8;
    const float4 g0 = *(const float4*)(gamma + c0);
    const float4 g1 = *(const float4*)(gamma + c0 + 4);
    const float4 b0 = *(const float4*)(beta + c0);
    const float4 b1 = *(const float4*)(beta + c0 + 4);
    const float4 a = xv[j * 2], b = xv[j * 2 + 1];
    f16x8 h;
    h[0] = (_Float16)((a.x - mu) * rs * g0.x + b0.x);
    h[1] = (_Float16)((a.y - mu) * rs * g0.y + b0.y);
    h[2] = (_Float16)((a.z - mu) * rs * g0.z + b0.z);
    h[3] = (_Float16)((a.w - mu) * rs * g0.w + b0.w);
    h[4] = (_Float16)((b.x - mu) * rs * g1.x + b1.x);
    h[5] = (_Float16)((b.y - mu) * rs * g1.y + b1.y);
    h[6] = (_Float16)((b.z - mu) * rs * g1.z + b1.z);
    h[7] = (_Float16)((b.w - mu) * rs * g1.w + b1.w);
    *(f16x8*)(H + (size_t)t * DIM + c0) = h;
  }
}

// ---------------- W1 fp32 -> f16 ----------------
__global__ __launch_bounds__(256) void w1cast_kernel(const float* __restrict__ W1,
                                                     _Float16* __restrict__ W1h) {
  const int i = (blockIdx.x * 256 + threadIdx.x) * 8;
  const float4 a = *(const float4*)(W1 + i);
  const float4 b = *(const float4*)(W1 + i + 4);
  f16x8 o;
  o[0] = (_Float16)a.x; o[1] = (_Float16)a.y; o[2] = (_Float16)a.z; o[3] = (_Float16)a.w;
  o[4] = (_Float16)b.x; o[5] = (_Float16)b.y; o[6] = (_Float16)b.z; o[7] = (_Float16)b.w;
  *(f16x8*)(W1h + i) = o;
}

// -------- gate partials: logitsP[ks] = X[:, ks] . Wg[:, ks]^T ----------
// 256x64 tile, 8x8 micro, 256 threads (4 waves): LDS reads per FMA halved vs
// 4x4 micro (4 b128 per 64 FMA). Store strides 260/68 -> <=2-way (free).
#define GT_M 256
#define PX   260
#define PW   68
__global__ __launch_bounds__(256) void gate_kernel(const float* __restrict__ X,
                                                   const float* __restrict__ Wg,
                                                   float* __restrict__ logitsP) {
  __shared__ float sX[16][PX];   // [k][m]
  __shared__ float sW[16][PW];   // [k][e]
  const int tid  = threadIdx.x;
  const int m0   = blockIdx.x * GT_M;
  const int k0   = blockIdx.y * KSL;
  const int srow = tid >> 2;      // 0..63 staging row base
  const int skq  = tid & 3;       // k-quad
  const int ty   = tid >> 3;      // 0..31 token group (8 tokens each)
  const int tx   = tid & 7;       // 0..7  expert group (8 experts)
  const float* xb = X  + (size_t)(m0 + srow) * DIM + k0 + skq * 4;
  const float* wb = Wg + (size_t)srow * DIM + k0 + skq * 4;
  float acc[8][8] = {};
  float4 rx[4], rw;
#pragma unroll
  for (int g = 0; g < 4; ++g) rx[g] = *(const float4*)(xb + (size_t)(g * 64) * DIM);
  rw = *(const float4*)wb;
  for (int kt = 0; kt < KSL; kt += 16) {
    __syncthreads();
#pragma unroll
    for (int g = 0; g < 4; ++g) {
      sX[skq * 4 + 0][srow + g * 64] = rx[g].x;
      sX[skq * 4 + 1][srow + g * 64] = rx[g].y;
      sX[skq * 4 + 2][srow + g * 64] = rx[g].z;
      sX[skq * 4 + 3][srow + g * 64] = rx[g].w;
    }
    sW[skq * 4 + 0][srow] = rw.x;
    sW[skq * 4 + 1][srow] = rw.y;
    sW[skq * 4 + 2][srow] = rw.z;
    sW[skq * 4 + 3][srow] = rw.w;
    const int ktn = (kt + 16 < KSL) ? kt + 16 : 0;   // harmless reload on last iter
#pragma unroll
    for (int g = 0; g < 4; ++g) rx[g] = *(const float4*)(xb + (size_t)(g * 64) * DIM + ktn);
    rw = *(const float4*)(wb + ktn);
    __syncthreads();
#pragma unroll
    for (int k = 0; k < 16; ++k) {
      const float4 a0 = *(const float4*)&sX[k][ty * 8];
      const float4 a1 = *(const float4*)&sX[k][ty * 8 + 4];
      const float4 b0 = *(const float4*)&sW[k][tx * 8];
      const float4 b1 = *(const float4*)&sW[k][tx * 8 + 4];
      const float av[8] = {a0.x, a0.y, a0.z, a0.w, a1.x, a1.y, a1.z, a1.w};
      const float bv[8] = {b0.x, b0.y, b0.z, b0.w, b1.x, b1.y, b1.z, b1.w};
#pragma unroll
      for (int i = 0; i < 8; ++i)
#pragma unroll
        for (int j = 0; j < 8; ++j) acc[i][j] += av[i] * bv[j];
    }
  }
  float* op = logitsP + (size_t)blockIdx.y * ((size_t)BS_TOK * NEXP)
            + (size_t)(m0 + ty * 8) * NEXP + tx * 8;
#pragma unroll
  for (int i = 0; i < 8; ++i) {
    float4 o0, o1;
    o0.x = acc[i][0]; o0.y = acc[i][1]; o0.z = acc[i][2]; o0.w = acc[i][3];
    o1.x = acc[i][4]; o1.y = acc[i][5]; o1.z = acc[i][6]; o1.w = acc[i][7];
    *(float4*)(op + (size_t)i * NEXP)     = o0;
    *(float4*)(op + (size_t)i * NEXP + 4) = o1;
  }
}

// ------- predictor GEMM: H1 = gelu(H . W1^T); z[t] += sum_n H1*W2 (fused) -------
// 256x256 tile, BK=64, 8 waves (2Mx4N), dbuf=2 (128 KB LDS). Per K-tile: all 8
// stage loads issued up-front and left in flight across 4 intra-tile phase
// barriers (T4: boundary vmcnt(0) finds them landed, ~zero stall). Each phase:
// {ds_read subtile; setprio(1); 16 MFMA; setprio(0); barrier} (T3+T5 stagger).
// k-octet XOR swizzle both-sides (T2, conflict-free within 8-lane groups).
// XCD-affine grid: the 4 blocks sharing an H m-panel land on one XCD's L2.
#define G2BM 256
#define G2BN 256
#define G2BK 64
#define G2NT (DIM / G2BK)   // 32 K-tiles

__global__ __launch_bounds__(512, 2) void g2_kernel(const _Float16* __restrict__ H,
                                                    const _Float16* __restrict__ W1h,
                                                    const float* __restrict__ W2,
                                                    float* __restrict__ diffz) {
  __shared__ __align__(16) _Float16 sA[2][G2BM * G2BK];
  __shared__ __align__(16) _Float16 sB[2][G2BN * G2BK];
  const int bid = blockIdx.x;
  const int xcd = bid & 7;
  const int loc = bid >> 3;                       // 0..31
  const int m0  = (xcd * 8 + (loc >> 2)) * G2BM;  // same-m blocks share an XCD
  const int n0  = (loc & 3) * G2BN;
  const int tid  = threadIdx.x;
  const int lane = tid & 63;
  const int w    = tid >> 6;
  const int wr   = w >> 2, wc = w & 3;            // 2 x 4 wave grid
  const int col  = lane & 15, quad = lane >> 4;
  const int c0   = col & 7;
  // staging: instr r covers rows [64r,64r+64); thread -> row 64r+(tid>>3),
  // LDS slot tid&7 (linear dest), global k-octet pre-swizzled:
  const int srow8 = tid >> 3;                     // 0..63
  const int ksw   = (tid & 7) ^ (srow8 & 7);      // LDS slot s of row r holds octet s^(r&7)
  const _Float16* gA = H   + (size_t)(m0 + srow8) * DIM + ksw * 8;
  const _Float16* gB = W1h + (size_t)(n0 + srow8) * DIM + ksw * 8;
  f32x4 acc[8][4] = {};
#define G2_STAGE(bf_, kt_)                                                                          \
  do {                                                                                              \
    __builtin_amdgcn_global_load_lds((GLOBAL_AS)(gA + (kt_)),                 (LDS_AS)(sA[bf_] + tid * 8), 16, 0, 0);          \
    __builtin_amdgcn_global_load_lds((GLOBAL_AS)(gA + (size_t)64  * DIM + (kt_)), (LDS_AS)(sA[bf_] + 4096 + tid * 8), 16, 0, 0);   \
    __builtin_amdgcn_global_load_lds((GLOBAL_AS)(gA + (size_t)128 * DIM + (kt_)), (LDS_AS)(sA[bf_] + 8192 + tid * 8), 16, 0, 0);   \
    __builtin_amdgcn_global_load_lds((GLOBAL_AS)(gA + (size_t)192 * DIM + (kt_)), (LDS_AS)(sA[bf_] + 12288 + tid * 8), 16, 0, 0);  \
    __builtin_amdgcn_global_load_lds((GLOBAL_AS)(gB + (kt_)),                 (LDS_AS)(sB[bf_] + tid * 8), 16, 0, 0);          \
    __builtin_amdgcn_global_load_lds((GLOBAL_AS)(gB + (size_t)64  * DIM + (kt_)), (LDS_AS)(sB[bf_] + 4096 + tid * 8), 16, 0, 0);   \
    __builtin_amdgcn_global_load_lds((GLOBAL_AS)(gB + (size_t)128 * DIM + (kt_)), (LDS_AS)(sB[bf_] + 8192 + tid * 8), 16, 0, 0);   \
    __builtin_amdgcn_global_load_lds((GLOBAL_AS)(gB + (size_t)192 * DIM + (kt_)), (LDS_AS)(sB[bf_] + 12288 + tid * 8), 16, 0, 0);  \
  } while (0)
  G2_STAGE(0, 0);
  asm volatile("s_waitcnt vmcnt(0)" ::: "memory");
  __builtin_amdgcn_s_barrier();
  int cur = 0;
  for (int t = 0; t < G2NT; ++t) {
    if (t + 1 < G2NT) G2_STAGE(cur ^ 1, (t + 1) * G2BK);   // in flight across all phases
    const _Float16* A = sA[cur];
    const _Float16* B = sB[cur];
    f16x8 af[4], bfr[4];
#pragma unroll
    for (int kh = 0; kh < 2; ++kh) {
      const int sqz = ((kh * 4 + quad) ^ c0) * 8;   // swizzled k-octet offset (f16 elems)
      // phase A: bf + af[0..3] -> quadrant (mi 0-3)
#pragma unroll
      for (int ni = 0; ni < 4; ++ni)
        bfr[ni] = *(const f16x8*)(B + (wc * 64 + ni * 16 + col) * G2BK + sqz);
#pragma unroll
      for (int mi = 0; mi < 4; ++mi)
        af[mi] = *(const f16x8*)(A + (wr * 128 + mi * 16 + col) * G2BK + sqz);
      __builtin_amdgcn_s_setprio(1);
#pragma unroll
      for (int mi = 0; mi < 4; ++mi)
#pragma unroll
        for (int ni = 0; ni < 4; ++ni)
          acc[mi][ni] = __builtin_amdgcn_mfma_f32_16x16x32_f16(af[mi], bfr[ni], acc[mi][ni], 0, 0, 0);
      __builtin_amdgcn_s_setprio(0);
      __builtin_amdgcn_s_barrier();
      // phase B: af[4..7] -> quadrant (mi 4-7), bfr reused
#pragma unroll
      for (int mi = 0; mi < 4; ++mi)
        af[mi] = *(const f16x8*)(A + (wr * 128 + (mi + 4) * 16 + col) * G2BK + sqz);
      __builtin_amdgcn_s_setprio(1);
#pragma unroll
      for (int mi = 0; mi < 4; ++mi)
#pragma unroll
        for (int ni = 0; ni < 4; ++ni)
          acc[mi + 4][ni] = __builtin_amdgcn_mfma_f32_16x16x32_f16(af[mi], bfr[ni], acc[mi + 4][ni], 0, 0, 0);
      __builtin_amdgcn_s_setprio(0);
      __builtin_amdgcn_s_barrier();
    }
    // boundary: own stage loads landed (issued ~1 tile ago) -> near-zero wait
    if (t + 1 < G2NT) asm volatile("s_waitcnt vmcnt(0)" ::: "memory");
    __builtin_amdgcn_s_barrier();
    cur ^= 1;
  }
#undef G2_STAGE
  // epilogue: gelu -> * W2 -> reduce over the 256 n-cols this block owns
  float w2v[4];
#pragma unroll
  for (int ni = 0; ni < 4; ++ni) w2v[ni] = W2[n0 + wc * 64 + ni * 16 + col];
#pragma unroll
  for (int mi = 0; mi < 8; ++mi) {
#pragma unroll
    for (int reg = 0; reg < 4; ++reg) {
      float v = 0.f;
#pragma unroll
      for (int ni = 0; ni < 4; ++ni) v += gelu_f(acc[mi][ni][reg]) * w2v[ni];
      v += __shfl_xor(v, 1);
      v += __shfl_xor(v, 2);
      v += __shfl_xor(v, 4);
      v += __shfl_xor(v, 8);
      if (col == 0)
        atomicAdd(diffz + m0 + wr * 128 + mi * 16 + quad * 4 + reg, v);
    }
  }
}

// ---------------- per-token finalize: one wave per token, 32 tokens/block ----------------
__global__ __launch_bounds__(256) void finalize_kernel(const float* __restrict__ logitsP,
                                                       const float* __restrict__ diffz,
                                                       float* __restrict__ out_idx,
                                                       float* __restrict__ out_scores,
                                                       float* __restrict__ out_probs,
                                                       float* __restrict__ imp_acc,
                                                       float* __restrict__ load_acc) {
  const int tid  = threadIdx.x;
  const int w    = tid >> 6, lane = tid & 63;
  const size_t PS = (size_t)BS_TOK * NEXP;
  float acc_imp = 0.f, acc_load = 0.f;
  for (int it = 0; it < 8; ++it) {
    const int t    = blockIdx.x * 32 + it * 4 + w;
    const float* lp = logitsP + (size_t)t * NEXP + lane;
    const float L  = ((lp[0] + lp[PS]) + lp[2 * PS]) + lp[3 * PS];
    const float z  = diffz[t];
    const float d  = 1.0f / (1.0f + expf(-z));
    const float l  = L / (1.0f + d);          // TEMP == 1
    // softmax
    float m = l;
#pragma unroll
    for (int off = 32; off > 0; off >>= 1) m = fmaxf(m, __shfl_xor(m, off));
    float p = expf(l - m);
    float s = p;
#pragma unroll
    for (int off = 32; off > 0; off >>= 1) s += __shfl_xor(s, off);
    p /= s;
    // top-1 (jax tie-break: lower index wins)
    float v = l; int bi = lane;
#pragma unroll
    for (int off = 32; off > 0; off >>= 1) {
      const float ov = __shfl_xor(v, off);
      const int   oi = __shfl_xor(bi, off);
      if (ov > v || (ov == v && oi < bi)) { v = ov; bi = oi; }
    }
    const int i1 = bi;
    // top-2
    float v2 = (lane == i1) ? -INFINITY : l;
    int bi2 = lane;
#pragma unroll
    for (int off = 32; off > 0; off >>= 1) {
      const float ov = __shfl_xor(v2, off);
      const int   oi = __shfl_xor(bi2, off);
      if (ov > v2 || (ov == v2 && oi < bi2)) { v2 = ov; bi2 = oi; }
    }
    const int i2 = bi2;
    const float p1 = __shfl(p, i1);
    const float p2 = __shfl(p, i2);
    const float s1 = (1.0f - p1) + p1;        // straight-through, fp32-faithful
    const float s2 = (1.0f - p2) + p2;
    const float den = fmaxf(s1 + s2, 1e-9f);
    if (lane == 0) {
      out_idx[t * 2]        = (float)i1;
      out_idx[t * 2 + 1]    = (float)i2;
      out_scores[t * 2]     = s1 / den;
      out_scores[t * 2 + 1] = s2 / den;
    }
    out_probs[(size_t)t * NEXP + lane] = p;
    acc_imp  += p;
    acc_load += (lane == i1 || lane == i2) ? 1.0f : 0.0f;
  }
  __shared__ float s_imp[256];
  __shared__ float s_hard[256];
  s_imp[tid]  = acc_imp;
  s_hard[tid] = acc_load;
  __syncthreads();
  if (tid < 64) {
    const float si = s_imp[tid] + s_imp[64 + tid] + s_imp[128 + tid] + s_imp[192 + tid];
    const float sl = s_hard[tid] + s_hard[64 + tid] + s_hard[128 + tid] + s_hard[192 + tid];
    atomicAdd(imp_acc + tid, si);
    atomicAdd(load_acc + tid, sl);
  }
}

// ---------------- importance/load scale ----------------
__global__ void scale_kernel(const float* __restrict__ acc,
                             float* __restrict__ out_imp,
                             float* __restrict__ out_load) {
  const int tid = threadIdx.x;
  const float inv = 1.0f / 16384.0f;
  if (tid < 64)       out_imp[tid]        = acc[tid] * inv;
  else if (tid < 128) out_load[tid - 64]  = acc[tid] * inv;
}

extern "C" void kernel_launch(void* const* d_in, const int* in_sizes, int n_in,
                              void* d_out, int out_size, void* d_ws, size_t ws_size,
                              hipStream_t stream) {
  (void)in_sizes; (void)n_in; (void)out_size; (void)ws_size;
  const float* X     = (const float*)d_in[0];
  const float* Wg    = (const float*)d_in[1];
  const float* gamma = (const float*)d_in[2];
  const float* beta  = (const float*)d_in[3];
  const float* W1    = (const float*)d_in[4];
  const float* W2    = (const float*)d_in[5];
  float* out = (float*)d_out;

  char* ws = (char*)d_ws;
  _Float16* H       = (_Float16*)(ws);                    // 64 MB
  _Float16* W1h     = (_Float16*)(ws + 67108864ull);      // 4 MB
  float*    logitsP = (float*)  (ws + 71303168ull);       // 16 MB (4 k-split partials)
  float*    diffz   = (float*)  (ws + 88080384ull);       // 64 KB
  float*    accs    = (float*)  (ws + 88145920ull);       // 512 B (imp[64], load[64])

  // out layout (all float32): idx[32768] | scores[32768] | probs[1048576] | imp[64] | load[64]
  float* out_idx    = out;
  float* out_scores = out + 32768;
  float* out_probs  = out + 65536;
  float* out_imp    = out + 1114112;
  float* out_load   = out + 1114176;

  hipMemsetAsync(diffz, 0, 65536ull + 512ull, stream);
  // order: gate streams cold X; ln re-reads X L3-warm; g2 reads H L3-warm.
  gate_kernel<<<dim3(BS_TOK / GT_M, GKS), 256, 0, stream>>>(X, Wg, logitsP);
  ln_kernel<<<BS_TOK / 4, 256, 0, stream>>>(X, gamma, beta, H);
  w1cast_kernel<<<(DHID * DIM) / (256 * 8), 256, 0, stream>>>(W1, W1h);
  g2_kernel<<<(DHID / G2BN) * (BS_TOK / G2BM), 512, 0, stream>>>(H, W1h, W2, diffz);
  finalize_kernel<<<BS_TOK / 32, 256, 0, stream>>>(logitsP, diffz, out_idx, out_scores,
                                                   out_probs, accs, accs + 64);
  scale_kernel<<<1, 128, 0, stream>>>(accs, out_imp, out_load);
}

// Round 4
// 359.451 us; speedup vs baseline: 1.1987x; 1.0202x over previous
//
#include <hip/hip_runtime.h>
#include <math.h>

#define BS_TOK 16384   // B*S
#define DIM    2048    // D
#define NEXP   64      // E
#define DHID   1024    // D/2
#define GKS    4       // gate k-split
#define KSL    (DIM / GKS)

typedef __attribute__((ext_vector_type(8))) _Float16 f16x8;
typedef __attribute__((ext_vector_type(4))) float    f32x4;

#define GLOBAL_AS const __attribute__((address_space(1))) void*
#define LDS_AS    __attribute__((address_space(3))) void*

__device__ __forceinline__ float gelu_f(float x) {
  return 0.5f * x * (1.0f + erff(x * 0.70710678118654752440f));
}

// ---------------- LayerNorm -> f16 H : one wave per token, no LDS ----------------
__global__ __launch_bounds__(256) void ln_kernel(const float* __restrict__ X,
                                                 const float* __restrict__ gamma,
                                                 const float* __restrict__ beta,
                                                 _Float16* __restrict__ H) {
  const int tid  = threadIdx.x;
  const int w    = tid >> 6, lane = tid & 63;
  const int t    = blockIdx.x * 4 + w;
  const float* xr = X + (size_t)t * DIM;
  float4 xv[8];
#pragma unroll
  for (int j = 0; j < 4; ++j) {
    const int c0 = (j * 64 + lane) * 8;
    xv[j * 2]     = *(const float4*)(xr + c0);
    xv[j * 2 + 1] = *(const float4*)(xr + c0 + 4);
  }
  float s = 0.f, q = 0.f;
#pragma unroll
  for (int j = 0; j < 8; ++j) {
    s += (xv[j].x + xv[j].y) + (xv[j].z + xv[j].w);
    q += (xv[j].x * xv[j].x + xv[j].y * xv[j].y) + (xv[j].z * xv[j].z + xv[j].w * xv[j].w);
  }
#pragma unroll
  for (int off = 32; off > 0; off >>= 1) {
    s += __shfl_xor(s, off);
    q += __shfl_xor(q, off);
  }
  const float mu  = s * (1.0f / DIM);
  const float var = q * (1.0f / DIM) - mu * mu;
  const float rs  = rsqrtf(var + 1e-5f);
#pragma unroll
  for (int j = 0; j < 4; ++j) {
    const int c0 = (j * 64 + lane) * 8;
    const float4 g0 = *(const float4*)(gamma + c0);
    const float4 g1 = *(const float4*)(gamma + c0 + 4);
    const float4 b0 = *(const float4*)(beta + c0);
    const float4 b1 = *(const float4*)(beta + c0 + 4);
    const float4 a = xv[j * 2], b = xv[j * 2 + 1];
    f16x8 h;
    h[0] = (_Float16)((a.x - mu) * rs * g0.x + b0.x);
    h[1] = (_Float16)((a.y - mu) * rs * g0.y + b0.y);
    h[2] = (_Float16)((a.z - mu) * rs * g0.z + b0.z);
    h[3] = (_Float16)((a.w - mu) * rs * g0.w + b0.w);
    h[4] = (_Float16)((b.x - mu) * rs * g1.x + b1.x);
    h[5] = (_Float16)((b.y - mu) * rs * g1.y + b1.y);
    h[6] = (_Float16)((b.z - mu) * rs * g1.z + b1.z);
    h[7] = (_Float16)((b.w - mu) * rs * g1.w + b1.w);
    *(f16x8*)(H + (size_t)t * DIM + c0) = h;
  }
}

// ---------------- W1 fp32 -> f16 ----------------
__global__ __launch_bounds__(256) void w1cast_kernel(const float* __restrict__ W1,
                                                     _Float16* __restrict__ W1h) {
  const int i = (blockIdx.x * 256 + threadIdx.x) * 8;
  const float4 a = *(const float4*)(W1 + i);
  const float4 b = *(const float4*)(W1 + i + 4);
  f16x8 o;
  o[0] = (_Float16)a.x; o[1] = (_Float16)a.y; o[2] = (_Float16)a.z; o[3] = (_Float16)a.w;
  o[4] = (_Float16)b.x; o[5] = (_Float16)b.y; o[6] = (_Float16)b.z; o[7] = (_Float16)b.w;
  *(f16x8*)(W1h + i) = o;
}

// -------- gate partials: logitsP[ks] = X[:, ks] . Wg[:, ks]^T ----------
// 256x64 tile, 8x8 micro, 256 threads (4 waves).
#define GT_M 256
#define PX   260
#define PW   68
__global__ __launch_bounds__(256) void gate_kernel(const float* __restrict__ X,
                                                   const float* __restrict__ Wg,
                                                   float* __restrict__ logitsP) {
  __shared__ float sX[16][PX];   // [k][m]
  __shared__ float sW[16][PW];   // [k][e]
  const int tid  = threadIdx.x;
  const int m0   = blockIdx.x * GT_M;
  const int k0   = blockIdx.y * KSL;
  const int srow = tid >> 2;      // 0..63 staging row base
  const int skq  = tid & 3;       // k-quad
  const int ty   = tid >> 3;      // 0..31 token group (8 tokens each)
  const int tx   = tid & 7;       // 0..7  expert group (8 experts)
  const float* xb = X  + (size_t)(m0 + srow) * DIM + k0 + skq * 4;
  const float* wb = Wg + (size_t)srow * DIM + k0 + skq * 4;
  float acc[8][8] = {};
  float4 rx[4], rw;
#pragma unroll
  for (int g = 0; g < 4; ++g) rx[g] = *(const float4*)(xb + (size_t)(g * 64) * DIM);
  rw = *(const float4*)wb;
  for (int kt = 0; kt < KSL; kt += 16) {
    __syncthreads();
#pragma unroll
    for (int g = 0; g < 4; ++g) {
      sX[skq * 4 + 0][srow + g * 64] = rx[g].x;
      sX[skq * 4 + 1][srow + g * 64] = rx[g].y;
      sX[skq * 4 + 2][srow + g * 64] = rx[g].z;
      sX[skq * 4 + 3][srow + g * 64] = rx[g].w;
    }
    sW[skq * 4 + 0][srow] = rw.x;
    sW[skq * 4 + 1][srow] = rw.y;
    sW[skq * 4 + 2][srow] = rw.z;
    sW[skq * 4 + 3][srow] = rw.w;
    const int ktn = (kt + 16 < KSL) ? kt + 16 : 0;   // harmless reload on last iter
#pragma unroll
    for (int g = 0; g < 4; ++g) rx[g] = *(const float4*)(xb + (size_t)(g * 64) * DIM + ktn);
    rw = *(const float4*)(wb + ktn);
    __syncthreads();
#pragma unroll
    for (int k = 0; k < 16; ++k) {
      const float4 a0 = *(const float4*)&sX[k][ty * 8];
      const float4 a1 = *(const float4*)&sX[k][ty * 8 + 4];
      const float4 b0 = *(const float4*)&sW[k][tx * 8];
      const float4 b1 = *(const float4*)&sW[k][tx * 8 + 4];
      const float av[8] = {a0.x, a0.y, a0.z, a0.w, a1.x, a1.y, a1.z, a1.w};
      const float bv[8] = {b0.x, b0.y, b0.z, b0.w, b1.x, b1.y, b1.z, b1.w};
#pragma unroll
      for (int i = 0; i < 8; ++i)
#pragma unroll
        for (int j = 0; j < 8; ++j) acc[i][j] += av[i] * bv[j];
    }
  }
  float* op = logitsP + (size_t)blockIdx.y * ((size_t)BS_TOK * NEXP)
            + (size_t)(m0 + ty * 8) * NEXP + tx * 8;
#pragma unroll
  for (int i = 0; i < 8; ++i) {
    float4 o0, o1;
    o0.x = acc[i][0]; o0.y = acc[i][1]; o0.z = acc[i][2]; o0.w = acc[i][3];
    o1.x = acc[i][4]; o1.y = acc[i][5]; o1.z = acc[i][6]; o1.w = acc[i][7];
    *(float4*)(op + (size_t)i * NEXP)     = o0;
    *(float4*)(op + (size_t)i * NEXP + 4) = o1;
  }
}

// ------- predictor GEMM: H1 = gelu(H . W1^T); z[t] += sum_n H1*W2 (fused) -------
// m201-style 8-phase-per-2-Ktiles schedule, here 4 phases per BK=64 tile:
// phase p = (kh=p>>1, m-half=p&1): {4 A-reads (+4 B-reads on kh entry);
// 2 stage loads; s_barrier; lgkmcnt(0)+sched_barrier; setprio(1); 16 MFMA;
// setprio(0); s_barrier}. ds_read latency hides under the barrier/other waves'
// MFMA region (T3 fine interleave); boundary vmcnt(0) merges with the phase-3
// trailing barrier (all outstanding loads are tile t+1's -> counted semantics).
// T2 k-octet XOR swizzle (conflict-free, verified 0 in r2/r3); XCD-affine grid.
#define G2BM 256
#define G2BN 256
#define G2BK 64
#define G2NT (DIM / G2BK)   // 32 K-tiles

__global__ __launch_bounds__(512, 2) void g2_kernel(const _Float16* __restrict__ H,
                                                    const _Float16* __restrict__ W1h,
                                                    const float* __restrict__ W2,
                                                    float* __restrict__ diffz) {
  __shared__ __align__(16) _Float16 sA[2][G2BM * G2BK];
  __shared__ __align__(16) _Float16 sB[2][G2BN * G2BK];
  const int bid = blockIdx.x;
  const int xcd = bid & 7;
  const int loc = bid >> 3;                       // 0..31
  const int m0  = (xcd * 8 + (loc >> 2)) * G2BM;  // same-m blocks share an XCD
  const int n0  = (loc & 3) * G2BN;
  const int tid  = threadIdx.x;
  const int lane = tid & 63;
  const int w    = tid >> 6;
  const int wr   = w >> 2, wc = w & 3;            // 2 x 4 wave grid
  const int col  = lane & 15, quad = lane >> 4;
  const int c0   = col & 7;
  const int srow8 = tid >> 3;                     // 0..63
  const int ksw   = (tid & 7) ^ (srow8 & 7);      // LDS slot s of row r holds octet s^(r&7)
  const _Float16* gA = H   + (size_t)(m0 + srow8) * DIM + ksw * 8;
  const _Float16* gB = W1h + (size_t)(n0 + srow8) * DIM + ksw * 8;
  f32x4 acc[8][4] = {};
#define G2_LDA(bf_, g_, kt_) \
  __builtin_amdgcn_global_load_lds((GLOBAL_AS)(gA + (size_t)(64 * (g_)) * DIM + (kt_)), \
                                   (LDS_AS)(sA[bf_] + (g_) * 4096 + tid * 8), 16, 0, 0)
#define G2_LDB(bf_, g_, kt_) \
  __builtin_amdgcn_global_load_lds((GLOBAL_AS)(gB + (size_t)(64 * (g_)) * DIM + (kt_)), \
                                   (LDS_AS)(sB[bf_] + (g_) * 4096 + tid * 8), 16, 0, 0)
  // prologue: tile 0 fully staged
  G2_LDA(0, 0, 0); G2_LDA(0, 1, 0); G2_LDA(0, 2, 0); G2_LDA(0, 3, 0);
  G2_LDB(0, 0, 0); G2_LDB(0, 1, 0); G2_LDB(0, 2, 0); G2_LDB(0, 3, 0);
  asm volatile("s_waitcnt vmcnt(0)" ::: "memory");
  __builtin_amdgcn_s_barrier();
  int cur = 0;
  for (int t = 0; t < G2NT; ++t) {
    const _Float16* A = sA[cur];
    const _Float16* B = sB[cur];
    const int nxt = cur ^ 1;
    const int nk  = (t + 1) * G2BK;
    const bool pf = (t + 1 < G2NT);
    f16x8 af[4], bfr[4];
#pragma unroll
    for (int kh = 0; kh < 2; ++kh) {
      const int sqz = ((kh * 4 + quad) ^ c0) * 8;   // swizzled k-octet offset (f16 elems)
      // ---- phase (kh,0): mi 0-3, B(kh) entry ----
#pragma unroll
      for (int ni = 0; ni < 4; ++ni)
        bfr[ni] = *(const f16x8*)(B + (wc * 64 + ni * 16 + col) * G2BK + sqz);
#pragma unroll
      for (int mi = 0; mi < 4; ++mi)
        af[mi] = *(const f16x8*)(A + (wr * 128 + mi * 16 + col) * G2BK + sqz);
      if (pf) {
        if (kh == 0) { G2_LDA(nxt, 0, nk); G2_LDA(nxt, 1, nk); }
        else         { G2_LDB(nxt, 0, nk); G2_LDB(nxt, 1, nk); }
      }
      __builtin_amdgcn_s_barrier();
      asm volatile("s_waitcnt lgkmcnt(0)" ::: "memory");
      __builtin_amdgcn_sched_barrier(0);
      __builtin_amdgcn_s_setprio(1);
#pragma unroll
      for (int mi = 0; mi < 4; ++mi)
#pragma unroll
        for (int ni = 0; ni < 4; ++ni)
          acc[mi][ni] = __builtin_amdgcn_mfma_f32_16x16x32_f16(af[mi], bfr[ni], acc[mi][ni], 0, 0, 0);
      __builtin_amdgcn_s_setprio(0);
      __builtin_amdgcn_s_barrier();
      // ---- phase (kh,1): mi 4-7, bfr reused ----
#pragma unroll
      for (int mi = 0; mi < 4; ++mi)
        af[mi] = *(const f16x8*)(A + (wr * 128 + (mi + 4) * 16 + col) * G2BK + sqz);
      if (pf) {
        if (kh == 0) { G2_LDA(nxt, 2, nk); G2_LDA(nxt, 3, nk); }
        else         { G2_LDB(nxt, 2, nk); G2_LDB(nxt, 3, nk); }
      }
      __builtin_amdgcn_s_barrier();
      asm volatile("s_waitcnt lgkmcnt(0)" ::: "memory");
      __builtin_amdgcn_sched_barrier(0);
      __builtin_amdgcn_s_setprio(1);
#pragma unroll
      for (int mi = 0; mi < 4; ++mi)
#pragma unroll
        for (int ni = 0; ni < 4; ++ni)
          acc[mi + 4][ni] = __builtin_amdgcn_mfma_f32_16x16x32_f16(af[mi], bfr[ni], acc[mi + 4][ni], 0, 0, 0);
      __builtin_amdgcn_s_setprio(0);
      if (kh == 1) {
        // boundary (merged with phase-3 trailing barrier): all outstanding
        // loads are tile t+1's -> vmcnt(0) == exact counted wait.
        asm volatile("s_waitcnt vmcnt(0)" ::: "memory");
      }
      __builtin_amdgcn_s_barrier();
    }
    cur ^= 1;
  }
#undef G2_LDA
#undef G2_LDB
  // epilogue: gelu -> * W2 -> reduce over the 256 n-cols this block owns
  float w2v[4];
#pragma unroll
  for (int ni = 0; ni < 4; ++ni) w2v[ni] = W2[n0 + wc * 64 + ni * 16 + col];
#pragma unroll
  for (int mi = 0; mi < 8; ++mi) {
#pragma unroll
    for (int reg = 0; reg < 4; ++reg) {
      float v = 0.f;
#pragma unroll
      for (int ni = 0; ni < 4; ++ni) v += gelu_f(acc[mi][ni][reg]) * w2v[ni];
      v += __shfl_xor(v, 1);
      v += __shfl_xor(v, 2);
      v += __shfl_xor(v, 4);
      v += __shfl_xor(v, 8);
      if (col == 0)
        atomicAdd(diffz + m0 + wr * 128 + mi * 16 + quad * 4 + reg, v);
    }
  }
}

// ---------------- per-token finalize: one wave per token, 32 tokens/block ----------------
__global__ __launch_bounds__(256) void finalize_kernel(const float* __restrict__ logitsP,
                                                       const float* __restrict__ diffz,
                                                       float* __restrict__ out_idx,
                                                       float* __restrict__ out_scores,
                                                       float* __restrict__ out_probs,
                                                       float* __restrict__ imp_acc,
                                                       float* __restrict__ load_acc) {
  const int tid  = threadIdx.x;
  const int w    = tid >> 6, lane = tid & 63;
  const size_t PS = (size_t)BS_TOK * NEXP;
  float acc_imp = 0.f, acc_load = 0.f;
  for (int it = 0; it < 8; ++it) {
    const int t    = blockIdx.x * 32 + it * 4 + w;
    const float* lp = logitsP + (size_t)t * NEXP + lane;
    const float L  = ((lp[0] + lp[PS]) + lp[2 * PS]) + lp[3 * PS];
    const float z  = diffz[t];
    const float d  = 1.0f / (1.0f + expf(-z));
    const float l  = L / (1.0f + d);          // TEMP == 1
    // softmax
    float m = l;
#pragma unroll
    for (int off = 32; off > 0; off >>= 1) m = fmaxf(m, __shfl_xor(m, off));
    float p = expf(l - m);
    float s = p;
#pragma unroll
    for (int off = 32; off > 0; off >>= 1) s += __shfl_xor(s, off);
    p /= s;
    // top-1 (jax tie-break: lower index wins)
    float v = l; int bi = lane;
#pragma unroll
    for (int off = 32; off > 0; off >>= 1) {
      const float ov = __shfl_xor(v, off);
      const int   oi = __shfl_xor(bi, off);
      if (ov > v || (ov == v && oi < bi)) { v = ov; bi = oi; }
    }
    const int i1 = bi;
    // top-2
    float v2 = (lane == i1) ? -INFINITY : l;
    int bi2 = lane;
#pragma unroll
    for (int off = 32; off > 0; off >>= 1) {
      const float ov = __shfl_xor(v2, off);
      const int   oi = __shfl_xor(bi2, off);
      if (ov > v2 || (ov == v2 && oi < bi2)) { v2 = ov; bi2 = oi; }
    }
    const int i2 = bi2;
    const float p1 = __shfl(p, i1);
    const float p2 = __shfl(p, i2);
    const float s1 = (1.0f - p1) + p1;        // straight-through, fp32-faithful
    const float s2 = (1.0f - p2) + p2;
    const float den = fmaxf(s1 + s2, 1e-9f);
    if (lane == 0) {
      out_idx[t * 2]        = (float)i1;
      out_idx[t * 2 + 1]    = (float)i2;
      out_scores[t * 2]     = s1 / den;
      out_scores[t * 2 + 1] = s2 / den;
    }
    out_probs[(size_t)t * NEXP + lane] = p;
    acc_imp  += p;
    acc_load += (lane == i1 || lane == i2) ? 1.0f : 0.0f;
  }
  __shared__ float s_imp[256];
  __shared__ float s_hard[256];
  s_imp[tid]  = acc_imp;
  s_hard[tid] = acc_load;
  __syncthreads();
  if (tid < 64) {
    const float si = s_imp[tid] + s_imp[64 + tid] + s_imp[128 + tid] + s_imp[192 + tid];
    const float sl = s_hard[tid] + s_hard[64 + tid] + s_hard[128 + tid] + s_hard[192 + tid];
    atomicAdd(imp_acc + tid, si);
    atomicAdd(load_acc + tid, sl);
  }
}

// ---------------- importance/load scale ----------------
__global__ void scale_kernel(const float* __restrict__ acc,
                             float* __restrict__ out_imp,
                             float* __restrict__ out_load) {
  const int tid = threadIdx.x;
  const float inv = 1.0f / 16384.0f;
  if (tid < 64)       out_imp[tid]        = acc[tid] * inv;
  else if (tid < 128) out_load[tid - 64]  = acc[tid] * inv;
}

extern "C" void kernel_launch(void* const* d_in, const int* in_sizes, int n_in,
                              void* d_out, int out_size, void* d_ws, size_t ws_size,
                              hipStream_t stream) {
  (void)in_sizes; (void)n_in; (void)out_size; (void)ws_size;
  const float* X     = (const float*)d_in[0];
  const float* Wg    = (const float*)d_in[1];
  const float* gamma = (const float*)d_in[2];
  const float* beta  = (const float*)d_in[3];
  const float* W1    = (const float*)d_in[4];
  const float* W2    = (const float*)d_in[5];
  float* out = (float*)d_out;

  char* ws = (char*)d_ws;
  _Float16* H       = (_Float16*)(ws);                    // 64 MB
  _Float16* W1h     = (_Float16*)(ws + 67108864ull);      // 4 MB
  float*    logitsP = (float*)  (ws + 71303168ull);       // 16 MB (4 k-split partials)
  float*    diffz   = (float*)  (ws + 88080384ull);       // 64 KB
  float*    accs    = (float*)  (ws + 88145920ull);       // 512 B (imp[64], load[64])

  // out layout (all float32): idx[32768] | scores[32768] | probs[1048576] | imp[64] | load[64]
  float* out_idx    = out;
  float* out_scores = out + 32768;
  float* out_probs  = out + 65536;
  float* out_imp    = out + 1114112;
  float* out_load   = out + 1114176;

  hipMemsetAsync(diffz, 0, 65536ull + 512ull, stream);
  // order: gate streams cold X; ln re-reads X L3-warm; g2 reads H L3-warm.
  gate_kernel<<<dim3(BS_TOK / GT_M, GKS), 256, 0, stream>>>(X, Wg, logitsP);
  ln_kernel<<<BS_TOK / 4, 256, 0, stream>>>(X, gamma, beta, H);
  w1cast_kernel<<<(DHID * DIM) / (256 * 8), 256, 0, stream>>>(W1, W1h);
  g2_kernel<<<(DHID / G2BN) * (BS_TOK / G2BM), 512, 0, stream>>>(H, W1h, W2, diffz);
  finalize_kernel<<<BS_TOK / 32, 256, 0, stream>>>(logitsP, diffz, out_idx, out_scores,
                                                   out_probs, accs, accs + 64);
  scale_kernel<<<1, 128, 0, stream>>>(accs, out_imp, out_load);
}